// Round 1
// baseline (193.707 us; speedup 1.0000x reference)
//
#include <hip/hip_runtime.h>
#include <stdint.h>

#define BB 32
#define NN 8000
#define MM 256
#define LL (NN + MM)        // 8256
#define NSAMP 512
#define MAXPOS 128
#define T2 1024
#define CH ((LL + T2 - 1) / T2)   // 9

// forbid fp-contract across this value (match numpy's non-FMA rounding)
__device__ __forceinline__ void opaquef(float& x) { asm volatile("" : "+v"(x)); }

// ---------------- kernel 1: per-(b,l) best-match + classification ----------
__global__ __launch_bounds__(256) void match_kernel(
    const float* __restrict__ boxes, const float* __restrict__ gt,
    int* __restrict__ packed)
{
    __shared__ float4 s_gt[MM];
    __shared__ float  s_a2[MM];
    __shared__ int    s_inv[MM];
    const int b = blockIdx.y, tid = threadIdx.x;
    {
        float4 v = ((const float4*)(gt + (size_t)b * MM * 4))[tid];
        s_gt[tid] = v;
        s_inv[tid] = (fmaxf(fmaxf(v.x, v.y), fmaxf(v.z, v.w)) < 0.0f) ? 1 : 0;
        s_a2[tid] = (v.z - v.x) * (v.w - v.y);   // (ymax-ymin)*(xmax-xmin)
    }
    __syncthreads();
    const int l = blockIdx.x * 256 + tid;
    if (l >= LL) return;

    float4 bx = (l < NN) ? ((const float4*)(boxes + (size_t)b * NN * 4))[l]
                         : s_gt[l - NN];
    const bool binv = fmaxf(fmaxf(bx.x, bx.y), fmaxf(bx.z, bx.w)) < 0.0f;

    float best = -2.0f; int bidx = 0;
    if (binv) {
        best = -1.0f; bidx = 0;   // all sim == -1 -> argmax = 0
    } else {
        float a1 = (bx.z - bx.x) * (bx.w - bx.y);
        opaquef(a1);
        for (int m = 0; m < MM; ++m) {
            float4 g = s_gt[m];
            float ih = fmaxf(fminf(bx.z, g.z) - fmaxf(bx.x, g.x), 0.0f);
            float iw = fmaxf(fminf(bx.w, g.w) - fmaxf(bx.y, g.y), 0.0f);
            float inter = ih * iw;
            opaquef(inter);
            float uni = (a1 + s_a2[m]) - inter;        // (a1+a2)-inter, numpy order
            float iou = (uni > 0.0f) ? (inter / uni) : 0.0f;  // IEEE div
            float sim = s_inv[m] ? -1.0f : iou;
            if (sim > best) { best = sim; bidx = m; }  // strict > = first argmax
        }
    }
    // searchsorted([0,.5,.5], right): <0 -> invalid(2), <0.5 -> neg(0), else pos(1)
    int cls = (best < 0.0f) ? 2 : ((best >= 0.5f) ? 1 : 0);
    packed[(size_t)b * LL + l] = cls | (bidx << 2);
}

// ---------------- kernel 2 helpers ----------------
__device__ int block_exscan(int v, int* scan, int tid, int* total)
{
    scan[tid] = v;
    __syncthreads();
    for (int off = 1; off < T2; off <<= 1) {
        int add = (tid >= off) ? scan[tid - off] : 0;
        __syncthreads();
        scan[tid] += add;
        __syncthreads();
    }
    int incl = scan[tid];
    if (total && tid == T2 - 1) *total = incl;
    __syncthreads();
    return incl - v;
}

// find K-th-largest key among {l : cls[l]==c}; returns threshold key and
// rem = number of ties at the threshold to take (in index order)
__device__ void radix_select(const uint32_t* key, const uint8_t* cls, int c, int K,
                             int* hist, int* sb, int tid,
                             uint32_t* thrKey, int* rem)
{
    uint32_t prefix = 0;
    int remaining = K;
    for (int round = 0; round < 4; ++round) {
        const int shift = 24 - 8 * round;
        for (int i = tid; i < 256; i += T2) hist[i] = 0;
        __syncthreads();
        const uint32_t pmask = (round == 0) ? 0u : (0xFFFFFFFFu << (shift + 8));
        for (int l = tid; l < LL; l += T2) {
            if (cls[l] == c) {
                uint32_t k = key[l];
                if ((k & pmask) == prefix) atomicAdd(&hist[(k >> shift) & 255], 1);
            }
        }
        __syncthreads();
        if (tid == 0) {
            int cum = 0, bin = 255;
            for (;; --bin) {
                cum += hist[bin];
                if (cum >= remaining || bin == 0) break;
            }
            sb[2] = bin;
            sb[3] = cum - hist[bin];   // count strictly above this bin
        }
        __syncthreads();
        const int bin = sb[2], above = sb[3];
        remaining -= above;
        prefix |= ((uint32_t)bin) << shift;
    }
    *thrKey = prefix;
    *rem = remaining;
}

__device__ void mark_select(const uint32_t* key, const uint8_t* cls, uint8_t* sel,
                            int c, uint32_t thrKey, int rem, int* scan, int tid)
{
    const int lo = tid * CH, hi = (lo + CH < LL) ? (lo + CH) : LL;
    int nt = 0;
    for (int l = lo; l < hi; ++l)
        if (cls[l] == c && key[l] == thrKey) ++nt;
    int base = block_exscan(nt, scan, tid, nullptr);
    for (int l = lo; l < hi; ++l) {
        if (cls[l] != c) continue;
        const uint32_t k = key[l];
        if (k > thrKey) sel[l] = 1;
        else if (k == thrKey) { if (base < rem) sel[l] = 1; ++base; }
    }
}

// ---------------- kernel 2: per-batch sampling + gather ----------------
__global__ __launch_bounds__(T2) void sample_kernel(
    const float* __restrict__ boxes, const float* __restrict__ gt,
    const int* __restrict__ gtc, const float* __restrict__ rnd,
    const int* __restrict__ packed, float* __restrict__ out)
{
    __shared__ uint32_t s_key[LL];
    __shared__ uint8_t  s_cls[LL];
    __shared__ uint8_t  s_sel[LL];
    __shared__ int s_scan[T2];
    __shared__ int s_hist[256];
    __shared__ int s_idx[NSAMP];
    __shared__ int s_b[6];
    const int b = blockIdx.x, tid = threadIdx.x;

    if (tid < 6) s_b[tid] = 0;
    __syncthreads();

    int locP = 0, locN = 0;
    for (int l = tid; l < LL; l += T2) {
        s_key[l] = __float_as_uint(rnd[(size_t)b * LL + l]);
        int p = packed[(size_t)b * LL + l];
        uint8_t c = (uint8_t)(p & 3);
        s_cls[l] = c;
        s_sel[l] = 0;
        locP += (c == 1);
        locN += (c == 0);
    }
    if (locP) atomicAdd(&s_b[0], locP);
    if (locN) atomicAdd(&s_b[1], locN);
    __syncthreads();
    const int P = s_b[0], Nn = s_b[1];

    // --- positives: top MAXPOS by rand (stable ties) ---
    const int posK = (P < MAXPOS) ? P : MAXPOS;
    if (P > MAXPOS) {
        uint32_t tk; int rem;
        radix_select(s_key, s_cls, 1, MAXPOS, s_hist, s_b, tid, &tk, &rem);
        mark_select(s_key, s_cls, s_sel, 1, tk, rem, s_scan, tid);
    } else {
        for (int l = tid; l < LL; l += T2) if (s_cls[l] == 1) s_sel[l] = 1;
    }
    __syncthreads();

    // --- negatives: top (512-posK) by rand ---
    const int negK = NSAMP - posK;
    if (Nn > negK) {
        uint32_t tk; int rem;
        radix_select(s_key, s_cls, 0, negK, s_hist, s_b, tid, &tk, &rem);
        mark_select(s_key, s_cls, s_sel, 0, tk, rem, s_scan, tid);
    } else {
        for (int l = tid; l < LL; l += T2) if (s_cls[l] == 0) s_sel[l] = 1;
    }
    __syncthreads();

    // --- stable compaction: selected ascending, then unselected ascending ---
    const int lo = tid * CH, hi = (lo + CH < LL) ? (lo + CH) : LL;
    int cs = 0;
    for (int l = lo; l < hi; ++l) cs += s_sel[l];
    int base = block_exscan(cs, s_scan, tid, &s_b[4]);
    __syncthreads();
    const int S = s_b[4];
    for (int l = lo; l < hi; ++l)
        if (s_sel[l]) { if (base < NSAMP) s_idx[base] = l; ++base; }

    int cu = 0;
    for (int l = lo; l < hi; ++l) cu += (s_sel[l] == 0);
    int base2 = block_exscan(cu, s_scan, tid, nullptr) + S;
    for (int l = lo; l < hi; ++l)
        if (!s_sel[l]) { if (base2 < NSAMP) s_idx[base2] = l; ++base2; }
    __syncthreads();

    // --- gather + write all 4 outputs (ints written as float values) ---
    if (tid < NSAMP) {
        const int l = s_idx[tid];
        float4 bx = (l < NN) ? ((const float4*)(boxes + (size_t)b * NN * 4))[l]
                             : ((const float4*)(gt + (size_t)b * MM * 4))[l - NN];
        const int p = packed[(size_t)b * LL + l];
        const int c = p & 3, mi = p >> 2;
        const bool bg = (c != 1);          // background = matched_val < 0.5
        float4 gb = make_float4(0.f, 0.f, 0.f, 0.f);
        int cl = 0, si = -1;
        if (!bg) {
            gb = ((const float4*)(gt + (size_t)b * MM * 4))[mi];
            cl = gtc[(size_t)b * MM + mi];
            si = mi;
        }
        const size_t rk = (size_t)b * NSAMP + tid;
        ((float4*)out)[rk] = bx;                                   // rois
        ((float4*)(out + (size_t)BB * NSAMP * 4))[rk] = gb;        // sampled_gt_boxes
        out[(size_t)2 * BB * NSAMP * 4 + rk] = (float)cl;          // sampled_gt_classes
        out[(size_t)2 * BB * NSAMP * 4 + (size_t)BB * NSAMP + rk] = (float)si; // indices
    }
}

extern "C" void kernel_launch(void* const* d_in, const int* in_sizes, int n_in,
                              void* d_out, int out_size, void* d_ws, size_t ws_size,
                              hipStream_t stream)
{
    const float* boxes = (const float*)d_in[0];   // [32,8000,4] f32
    const float* gt    = (const float*)d_in[1];   // [32,256,4]  f32
    const int*   gtc   = (const int*)  d_in[2];   // [32,256]    i32
    const float* rnd   = (const float*)d_in[3];   // [32,8256]   f32
    float* out = (float*)d_out;
    int* packed = (int*)d_ws;                     // BB*LL ints = 1.06 MB

    dim3 g1((LL + 255) / 256, BB);
    match_kernel<<<g1, 256, 0, stream>>>(boxes, gt, packed);
    sample_kernel<<<BB, T2, 0, stream>>>(boxes, gt, gtc, rnd, packed, out);
}

// Round 2
// 102.162 us; speedup vs baseline: 1.8961x; 1.8961x over previous
//
#include <hip/hip_runtime.h>
#include <stdint.h>

#define BB 32
#define NN 8000
#define MM 256
#define LL (NN + MM)        // 8256
#define NSAMP 512
#define MAXPOS 128
#define T2 1024
#define CH ((LL + T2 - 1) / T2)   // 9

// forbid fp-contract across this value (match numpy's non-FMA rounding)
__device__ __forceinline__ void opaquef(float& x) { asm volatile("" : "+v"(x)); }

// ---------------- kernel 1: per-(b,l) best-match + classification ----------
__global__ __launch_bounds__(256) void match_kernel(
    const float* __restrict__ boxes, const float* __restrict__ gt,
    int* __restrict__ packed)
{
    __shared__ float4 s_gt[MM];
    __shared__ float  s_a2[MM];
    const int b = blockIdx.y, tid = threadIdx.x;
    {
        float4 v = ((const float4*)(gt + (size_t)b * MM * 4))[tid];
        s_gt[tid] = v;
        s_a2[tid] = (v.z - v.x) * (v.w - v.y);   // invalid gt (-1,-1,-1,-1) -> 0
    }
    __syncthreads();
    const int l = blockIdx.x * 256 + tid;
    if (l >= LL) return;

    float4 bx = (l < NN) ? ((const float4*)(boxes + (size_t)b * NN * 4))[l]
                         : s_gt[l - NN];
    const bool binv = fmaxf(fmaxf(bx.x, bx.y), fmaxf(bx.z, bx.w)) < 0.0f;

    float best = -2.0f; int bidx = 0;
    if (binv) {
        best = -1.0f; bidx = 0;   // all sim == -1 -> argmax = 0
    } else {
        // For a VALID box, an invalid gt yields inter=0, a2=0 -> iou=0 here
        // (reference uses -1). Max over the row is >=0 and its first argmax is
        // always at some valid gt (m<192, all invalid gts are m>=192), so the
        // max value and the argmax index are unchanged.
        float a1 = (bx.z - bx.x) * (bx.w - bx.y);
        opaquef(a1);
        #pragma unroll 4
        for (int m = 0; m < MM; ++m) {
            float4 g = s_gt[m];
            float ih = fmaxf(fminf(bx.z, g.z) - fmaxf(bx.x, g.x), 0.0f);
            float iw = fmaxf(fminf(bx.w, g.w) - fmaxf(bx.y, g.y), 0.0f);
            float inter = ih * iw;
            opaquef(inter);
            float uni = (a1 + s_a2[m]) - inter;        // (a1+a2)-inter, numpy order
            float sim = (uni > 0.0f) ? (inter / uni) : 0.0f;  // IEEE div
            if (sim > best) { best = sim; bidx = m; }  // strict > = first argmax
        }
    }
    // searchsorted([0,.5,.5], right): <0 -> invalid(2), <0.5 -> neg(0), else pos(1)
    int cls = (best < 0.0f) ? 2 : ((best >= 0.5f) ? 1 : 0);
    packed[(size_t)b * LL + l] = cls | (bidx << 2);
}

// ---------------- fast block exclusive scan (1024 thr = 16 waves) ----------
// Returns exclusive prefix of v. After return (and until the next call
// overwrites wt), wt[15] holds the block total. 2 syncthreads.
__device__ __forceinline__ int block_exscan_fast(int v, int* wt, int tid)
{
    const int lane = tid & 63, w = tid >> 6;
    int x = v;
    #pragma unroll
    for (int off = 1; off < 64; off <<= 1) {
        int y = __shfl_up(x, off);
        if (lane >= off) x += y;
    }
    if (lane == 63) wt[w] = x;
    __syncthreads();
    if (tid < 64) {
        int t = (tid < 16) ? wt[tid] : 0;
        #pragma unroll
        for (int off = 1; off < 16; off <<= 1) {
            int y = __shfl_up(t, off);
            if (tid >= off) t += y;
        }
        if (tid < 16) wt[tid] = t;
    }
    __syncthreads();
    return ((w > 0) ? wt[w - 1] : 0) + x - v;
}

// find K-th-largest key among {l : cls[l]==c}; returns threshold key and
// rem = number of ties at the threshold to take (in index order)
__device__ void radix_select(const uint32_t* key, const uint8_t* cls, int c, int K,
                             int* hist, int* sb, int* wt, int tid,
                             uint32_t* thrKey, int* rem)
{
    uint32_t prefix = 0;
    int remaining = K;
    for (int round = 0; round < 4; ++round) {
        const int shift = 24 - 8 * round;
        if (tid < 256) hist[tid] = 0;
        __syncthreads();
        const uint32_t pmask = (round == 0) ? 0u : (0xFFFFFFFFu << (shift + 8));
        for (int l = tid; l < LL; l += T2) {
            if (cls[l] == c) {
                uint32_t k = key[l];
                if ((k & pmask) == prefix) atomicAdd(&hist[(k >> shift) & 255], 1);
            }
        }
        __syncthreads();
        // parallel bin search: suffix sums via reversed exclusive scan
        int h = (tid < 256) ? hist[255 - tid] : 0;
        int above = block_exscan_fast(h, wt, tid);   // sum over bins > (255-tid)
        if (tid < 256) {
            if (above < remaining && above + h >= remaining) {
                sb[2] = 255 - tid;   // unique crossing bin
                sb[3] = above;
            }
        }
        __syncthreads();
        const int bin = sb[2], abv = sb[3];
        remaining -= abv;
        prefix |= ((uint32_t)bin) << shift;
        __syncthreads();   // protect sb reads vs any later writes
    }
    *thrKey = prefix;
    *rem = remaining;
}

__device__ void mark_select(const uint32_t* key, const uint8_t* cls, uint8_t* sel,
                            int c, uint32_t thrKey, int rem, int* wt, int tid)
{
    const int lo = tid * CH, hi = (lo + CH < LL) ? (lo + CH) : LL;
    int nt = 0;
    for (int l = lo; l < hi; ++l)
        if (cls[l] == c && key[l] == thrKey) ++nt;
    int base = block_exscan_fast(nt, wt, tid);
    for (int l = lo; l < hi; ++l) {
        if (cls[l] != c) continue;
        const uint32_t k = key[l];
        if (k > thrKey) sel[l] = 1;
        else if (k == thrKey) { if (base < rem) sel[l] = 1; ++base; }
    }
}

// ---------------- kernel 2: per-batch sampling + gather ----------------
__global__ __launch_bounds__(T2) void sample_kernel(
    const float* __restrict__ boxes, const float* __restrict__ gt,
    const int* __restrict__ gtc, const float* __restrict__ rnd,
    const int* __restrict__ packed, float* __restrict__ out)
{
    __shared__ uint32_t s_key[LL];
    __shared__ uint8_t  s_cls[LL];
    __shared__ uint8_t  s_sel[LL];
    __shared__ int s_warp[16];
    __shared__ int s_hist[256];
    __shared__ int s_idx[NSAMP];
    __shared__ int s_b[6];
    const int b = blockIdx.x, tid = threadIdx.x;
    const int lane = tid & 63;

    if (tid < 6) s_b[tid] = 0;
    __syncthreads();

    int locP = 0, locN = 0;
    for (int l = tid; l < LL; l += T2) {
        s_key[l] = __float_as_uint(rnd[(size_t)b * LL + l]);
        int p = packed[(size_t)b * LL + l];
        uint8_t c = (uint8_t)(p & 3);
        s_cls[l] = c;
        s_sel[l] = 0;
        locP += (c == 1);
        locN += (c == 0);
    }
    #pragma unroll
    for (int off = 32; off; off >>= 1) {
        locP += __shfl_xor(locP, off);
        locN += __shfl_xor(locN, off);
    }
    if (lane == 0) { atomicAdd(&s_b[0], locP); atomicAdd(&s_b[1], locN); }
    __syncthreads();
    const int P = s_b[0], Nn = s_b[1];

    // --- positives: top MAXPOS by rand (stable ties) ---
    const int posK = (P < MAXPOS) ? P : MAXPOS;
    if (P > MAXPOS) {
        uint32_t tk; int rem;
        radix_select(s_key, s_cls, 1, MAXPOS, s_hist, s_b, s_warp, tid, &tk, &rem);
        mark_select(s_key, s_cls, s_sel, 1, tk, rem, s_warp, tid);
    } else {
        for (int l = tid; l < LL; l += T2) if (s_cls[l] == 1) s_sel[l] = 1;
    }
    __syncthreads();

    // --- negatives: top (512-posK) by rand ---
    const int negK = NSAMP - posK;
    if (Nn > negK) {
        uint32_t tk; int rem;
        radix_select(s_key, s_cls, 0, negK, s_hist, s_b, s_warp, tid, &tk, &rem);
        mark_select(s_key, s_cls, s_sel, 0, tk, rem, s_warp, tid);
    } else {
        for (int l = tid; l < LL; l += T2) if (s_cls[l] == 0) s_sel[l] = 1;
    }
    __syncthreads();

    // --- stable compaction: selected ascending, then unselected ascending ---
    const int lo = tid * CH, hi = (lo + CH < LL) ? (lo + CH) : LL;
    int cs = 0;
    for (int l = lo; l < hi; ++l) cs += s_sel[l];
    int base = block_exscan_fast(cs, s_warp, tid);
    const int S = s_warp[16 - 1];            // block total (valid until next scan)
    for (int l = lo; l < hi; ++l)
        if (s_sel[l]) { if (base < NSAMP) s_idx[base] = l; ++base; }

    int cu = 0;
    for (int l = lo; l < hi; ++l) cu += (s_sel[l] == 0);
    __syncthreads();                          // protect s_warp[15] reads above
    int base2 = block_exscan_fast(cu, s_warp, tid) + S;
    for (int l = lo; l < hi; ++l)
        if (!s_sel[l]) { if (base2 < NSAMP) s_idx[base2] = l; ++base2; }
    __syncthreads();

    // --- gather + write all 4 outputs (ints written as float values) ---
    if (tid < NSAMP) {
        const int l = s_idx[tid];
        float4 bx = (l < NN) ? ((const float4*)(boxes + (size_t)b * NN * 4))[l]
                             : ((const float4*)(gt + (size_t)b * MM * 4))[l - NN];
        const int p = packed[(size_t)b * LL + l];
        const int c = p & 3, mi = p >> 2;
        const bool bg = (c != 1);          // background = matched_val < 0.5
        float4 gb = make_float4(0.f, 0.f, 0.f, 0.f);
        int cl = 0, si = -1;
        if (!bg) {
            gb = ((const float4*)(gt + (size_t)b * MM * 4))[mi];
            cl = gtc[(size_t)b * MM + mi];
            si = mi;
        }
        const size_t rk = (size_t)b * NSAMP + tid;
        ((float4*)out)[rk] = bx;                                   // rois
        ((float4*)(out + (size_t)BB * NSAMP * 4))[rk] = gb;        // sampled_gt_boxes
        out[(size_t)2 * BB * NSAMP * 4 + rk] = (float)cl;          // sampled_gt_classes
        out[(size_t)2 * BB * NSAMP * 4 + (size_t)BB * NSAMP + rk] = (float)si; // indices
    }
}

extern "C" void kernel_launch(void* const* d_in, const int* in_sizes, int n_in,
                              void* d_out, int out_size, void* d_ws, size_t ws_size,
                              hipStream_t stream)
{
    const float* boxes = (const float*)d_in[0];   // [32,8000,4] f32
    const float* gt    = (const float*)d_in[1];   // [32,256,4]  f32
    const int*   gtc   = (const int*)  d_in[2];   // [32,256]    i32
    const float* rnd   = (const float*)d_in[3];   // [32,8256]   f32
    float* out = (float*)d_out;
    int* packed = (int*)d_ws;                     // BB*LL ints = 1.06 MB

    dim3 g1((LL + 255) / 256, BB);
    match_kernel<<<g1, 256, 0, stream>>>(boxes, gt, packed);
    sample_kernel<<<BB, T2, 0, stream>>>(boxes, gt, gtc, rnd, packed, out);
}